// Round 6
// baseline (481.205 us; speedup 1.0000x reference)
//
#include <hip/hip_runtime.h>

// CRF Viterbi forward decode — R5: split serial state recursion (k1) from
// embarrassingly-parallel backpointer argmax (k2).
// potentials: [1024, 512, 48] f32, transition: [48, 48] f32.
// out = backpointers [1024, 511, 48] (as float values) ++ scores [1024, 48] f32.
//
// R4 post-mortem: fused kernel ran ~340 instr/step (vs 175 in source) — the
// loop-carried cand[48] for the deferred scan forced AGPR shuttling, and at
// exactly 1 wave/SIMD (B=1024) the 47-deep scan chain latency was naked.
// R5: k1 keeps only the serial recursion (no scan, no cand liveness; stores
// state_t into the bp slot [b,t,:] — exact slot count, no workspace). k2
// recomputes cand = state + tcol (bit-identical) per row at 4+ waves/SIMD
// and overwrites rows with backpointers in place (read-before-write is
// program-ordered within the single owning wave).

constexpr int B_ = 1024;
constexpr int T_ = 512;
constexpr int K_ = 48;

// ---------------------------------------------------------------- kernel 1
__global__ __launch_bounds__(64, 1) void crf_state_kernel(
    const float* __restrict__ pot,
    const float* __restrict__ trans,
    float* __restrict__ out)
{
    const int b = blockIdx.x;
    const int j = threadIdx.x;  // 0..47 = destination tag

    __shared__ __align__(16) float stv[K_];

    float tcol[K_];
    #pragma unroll
    for (int i = 0; i < K_; ++i) tcol[i] = trans[i * K_ + j];

    const float* pp = pot + (size_t)b * T_ * K_ + j;
    float* stout    = out + ((size_t)b * (T_ - 1) + 1) * K_ + j;  // slots t=1..510
    float* scout    = out + (size_t)B_ * (T_ - 1) * K_ + (size_t)b * K_ + j;

    float myst = pp[0];
    stv[j] = myst;
    __builtin_amdgcn_wave_barrier();

    auto step = [&](float pcur, bool do_store) {
        // Batched broadcast reads (pipelined lgkmcnt).
        float4 sv[12];
        const float4* stv4 = (const float4*)stv;
        #pragma unroll
        for (int c = 0; c < 12; ++c) sv[c] = stv4[c];
        __builtin_amdgcn_wave_barrier();

        float cand[K_];
        #pragma unroll
        for (int c = 0; c < 12; ++c) {
            cand[4 * c + 0] = sv[c].x + tcol[4 * c + 0];
            cand[4 * c + 1] = sv[c].y + tcol[4 * c + 1];
            cand[4 * c + 2] = sv[c].z + tcol[4 * c + 2];
            cand[4 * c + 3] = sv[c].w + tcol[4 * c + 3];
        }
        // Ternary max tree -> v_max3_f32 (24 ops, depth 4).
        float m1[16];
        #pragma unroll
        for (int k = 0; k < 16; ++k)
            m1[k] = fmaxf(fmaxf(cand[3 * k], cand[3 * k + 1]), cand[3 * k + 2]);
        float m2[6];
        #pragma unroll
        for (int k = 0; k < 5; ++k)
            m2[k] = fmaxf(fmaxf(m1[3 * k], m1[3 * k + 1]), m1[3 * k + 2]);
        m2[5] = m1[15];
        float mm = fmaxf(fmaxf(fmaxf(m2[0], m2[1]), m2[2]),
                         fmaxf(fmaxf(m2[3], m2[4]), m2[5]));

        myst = pcur + mm;
        stv[j] = myst;                    // feeds next step ASAP
        __builtin_amdgcn_wave_barrier();

        if (do_store) { *stout = myst; stout += K_; }
    };

    // t=1 potential + prefetch t=2..7.
    float p1 = pp[(size_t)1 * K_];
    float pbuf[6];
    #pragma unroll
    for (int u = 0; u < 6; ++u) pbuf[u] = pp[(size_t)(2 + u) * K_];

    step(p1, true);  // t = 1

    for (int t0 = 2; t0 <= 500; t0 += 6) {   // 84 chunks: t = 2..505
        float pc[6];
        #pragma unroll
        for (int u = 0; u < 6; ++u) pc[u] = pbuf[u];
        #pragma unroll
        for (int u = 0; u < 6; ++u) pbuf[u] = pp[(size_t)(t0 + 6 + u) * K_]; // max 511, valid
        #pragma unroll
        for (int u = 0; u < 6; ++u) step(pc[u], true);
    }
    // Peeled last chunk: t = 506..511 (pbuf holds those potentials).
    #pragma unroll
    for (int u = 0; u < 5; ++u) step(pbuf[u], true);   // t = 506..510
    step(pbuf[5], false);                              // t = 511: no state store

    *scout = myst;
}

// ---------------------------------------------------------------- kernel 2
// Row (b, r), r in [0, 511): bp[b,r,j] = argmax_i(state_r[i] + trans[i][j]),
// first-occurrence ties. state_0 = pot[b,0,:]; state_r (r>=1) was written by
// k1 into the bp slot [b,r,:] and is overwritten here after being read.
__global__ __launch_bounds__(64, 4) void crf_bp_kernel(
    const float* __restrict__ pot,
    const float* __restrict__ trans,
    float* out)
{
    const int s = blockIdx.x;   // 0..7 : row-range chunk
    const int b = blockIdx.y;   // 0..1023
    const int j = threadIdx.x;  // 0..63; lanes >=48 compute garbage, don't store
    const int jj = j < K_ ? j : K_ - 1;

    float tcol[K_];
    #pragma unroll
    for (int i = 0; i < K_; ++i) tcol[i] = trans[i * K_ + jj];

    const int r0 = s * 64;
    const int r1 = (r0 + 64 < T_ - 1) ? r0 + 64 : T_ - 1;   // s=7 -> 63 rows

    for (int r = r0; r < r1; ++r) {
        const float* srow = out + ((size_t)b * (T_ - 1) + r) * K_;
        if (r == 0) srow = pot + (size_t)b * T_ * K_;

        // Wave-uniform address: 12 x 16B broadcast loads.
        float4 sv[12];
        const float4* srow4 = (const float4*)srow;
        #pragma unroll
        for (int c = 0; c < 12; ++c) sv[c] = srow4[c];

        float cand[K_];
        #pragma unroll
        for (int c = 0; c < 12; ++c) {
            cand[4 * c + 0] = sv[c].x + tcol[4 * c + 0];
            cand[4 * c + 1] = sv[c].y + tcol[4 * c + 1];
            cand[4 * c + 2] = sv[c].z + tcol[4 * c + 2];
            cand[4 * c + 3] = sv[c].w + tcol[4 * c + 3];
        }
        float m1[16];
        #pragma unroll
        for (int k = 0; k < 16; ++k)
            m1[k] = fmaxf(fmaxf(cand[3 * k], cand[3 * k + 1]), cand[3 * k + 2]);
        float m2[6];
        #pragma unroll
        for (int k = 0; k < 5; ++k)
            m2[k] = fmaxf(fmaxf(m1[3 * k], m1[3 * k + 1]), m1[3 * k + 2]);
        m2[5] = m1[15];
        float mm = fmaxf(fmaxf(fmaxf(m2[0], m2[1]), m2[2]),
                         fmaxf(fmaxf(m2[3], m2[4]), m2[5]));

        // First-occurrence argmax: reverse equality scan (exact: mm is one of
        // the cand values bitwise).
        int xx = K_ - 1;
        #pragma unroll
        for (int i = K_ - 2; i >= 0; --i)
            xx = (cand[i] == mm) ? i : xx;

        if (j < K_)
            out[((size_t)b * (T_ - 1) + r) * K_ + j] = (float)xx;
    }
}

extern "C" void kernel_launch(void* const* d_in, const int* in_sizes, int n_in,
                              void* d_out, int out_size, void* d_ws, size_t ws_size,
                              hipStream_t stream) {
    const float* pot   = (const float*)d_in[0];
    const float* trans = (const float*)d_in[1];
    float* out         = (float*)d_out;
    crf_state_kernel<<<dim3(B_), dim3(K_), 0, stream>>>(pot, trans, out);
    crf_bp_kernel<<<dim3(8, B_), dim3(64), 0, stream>>>(pot, trans, out);
}